// Round 2
// baseline (395.635 us; speedup 1.0000x reference)
//
#include <hip/hip_runtime.h>
#include <math.h>

// B=4, S=4096 -> 16384 tokens; H=4096; E=64; TOP_K=2
#define TOKENS 16384
#define HDIM 4096
#define NE 64

#define BM 64   // tokens per block
#define BK 64   // k per LDS stage (2 mfma k-steps)
#define LP 68   // logits LDS row stride (floats)

typedef float f32x4 __attribute__((ext_vector_type(4)));
typedef int i32x4 __attribute__((ext_vector_type(4)));
typedef __bf16 bf16x8 __attribute__((ext_vector_type(8)));

// f32 -> (hi, lo) bf16 split of 8 elements; each packed as 4xint = 8 bf16.
// a ~= hi + lo with residual ~2^-18|a| -> 4-term MFMA reproduces ~f32 accuracy.
__device__ __forceinline__ void split8(f32x4 v0, f32x4 v1, i32x4& h, i32x4& l) {
  float x[8];
#pragma unroll
  for (int j = 0; j < 4; ++j) { x[j] = v0[j]; x[4 + j] = v1[j]; }
  union { unsigned short u[8]; i32x4 v; } H, L;
#pragma unroll
  for (int j = 0; j < 8; ++j) {
    __bf16 hb = (__bf16)x[j];
    H.u[j] = __builtin_bit_cast(unsigned short, hb);
    L.u[j] = __builtin_bit_cast(unsigned short, (__bf16)(x[j] - (float)hb));
  }
  h = H.v; l = L.v;
}

__device__ __forceinline__ f32x4 mfma_bf16(i32x4 a, i32x4 b, f32x4 c) {
  return __builtin_amdgcn_mfma_f32_16x16x32_bf16(
      __builtin_bit_cast(bf16x8, a), __builtin_bit_cast(bf16x8, b), c, 0, 0, 0);
}

// Pre-split W (64x4096 f32 -> bf16 hi/lo in workspace). 1 MiB total, ~2 us,
// removes the per-block redundant W conversion (64x VALU redundancy).
__global__ __launch_bounds__(256) void convert_w(const float* __restrict__ W,
                                                 unsigned short* __restrict__ Wh,
                                                 unsigned short* __restrict__ Wl) {
  const int i = (blockIdx.x * 256 + threadIdx.x) * 8;
  f32x4 v0 = *(const f32x4*)(W + i);
  f32x4 v1 = *(const f32x4*)(W + i + 4);
  i32x4 h, l;
  split8(v0, v1, h, l);
  *(i32x4*)(Wh + i) = h;
  *(i32x4*)(Wl + i) = l;
}

// Fused router via split-bf16 MFMA: logits on the matrix pipe (f32 path was
// VALU-bound at ~55us; MFMA terms cost ~13us, leaving HBM ~43us as the floor).
// 256 blocks x 512 threads (8 waves). Per block: 64 tokens x 64 experts.
// LDS tiles XOR-swizzled (chunk ^= row&7): b128 reads/writes spread evenly
// over all 32 banks. Fragment layout (m89-verified): A/B lane l holds
// X[l&15][(l>>4)*8+j]; C/D col=lane&15, row=(lane>>4)*4+reg.
__global__ __launch_bounds__(512, 2) void router_mfma(const float* __restrict__ A,
                                                      const unsigned short* __restrict__ Wh,
                                                      const unsigned short* __restrict__ Wl,
                                                      float* __restrict__ out) {
  __shared__ __align__(16) unsigned short smem[4 * BM * BK];  // 32 KiB
  unsigned short* AhS = smem;                // [64 tok][64 k] bf16, swizzled
  unsigned short* AlS = smem + BM * BK;
  unsigned short* WhS = smem + 2 * BM * BK;  // [64 exp][64 k]
  unsigned short* WlS = smem + 3 * BM * BK;

  const int tid = threadIdx.x;
  const int bt = blockIdx.x;

  // staging map: row = tid>>3 (0..63), chunk = tid&7 (8 bf16 = 16 B each)
  const int srow = tid >> 3;
  const int sc = tid & 7;
  const int soff = srow * BK + ((sc ^ (srow & 7)) << 3);

  const float* Ab = A + (size_t)(bt * BM + srow) * HDIM + sc * 8;
  const unsigned short* Whb = Wh + srow * HDIM + sc * 8;  // srow<64 == E
  const unsigned short* Wlb = Wl + srow * HDIM + sc * 8;

  // fragment map: wave -> 16-token group x 32-expert half (2 16x16 tiles)
  const int lane = tid & 63;
  const int wv = tid >> 6;
  const int tg = wv & 3;
  const int eg = wv >> 2;
  const int l15 = lane & 15;
  const int l7 = lane & 7;
  const int fko = lane >> 4;            // k-subgroup 0..3
  const int arow = tg * 16 + l15;       // token row this lane reads
  const int brow = eg * 32 + l15;       // expert row (tile 0); tile 1 = +16

  f32x4 acc0 = {0.f, 0.f, 0.f, 0.f};
  f32x4 acc1 = {0.f, 0.f, 0.f, 0.f};

  // prologue: prefetch K-tile 0 into registers
  f32x4 a0 = *(const f32x4*)(Ab);
  f32x4 a1 = *(const f32x4*)(Ab + 4);
  i32x4 whr = *(const i32x4*)(Whb);
  i32x4 wlr = *(const i32x4*)(Wlb);

  for (int kc = BK;; kc += BK) {
    // stage current tile (A converted in-flight; W already bf16)
    i32x4 ah, al;
    split8(a0, a1, ah, al);
    *(i32x4*)&AhS[soff] = ah;
    *(i32x4*)&AlS[soff] = al;
    *(i32x4*)&WhS[soff] = whr;
    *(i32x4*)&WlS[soff] = wlr;
    __syncthreads();

    // prefetch next tile (in flight across the compute below)
    if (kc < HDIM) {
      a0 = *(const f32x4*)(Ab + kc);
      a1 = *(const f32x4*)(Ab + kc + 4);
      whr = *(const i32x4*)(Whb + kc);
      wlr = *(const i32x4*)(Wlb + kc);
    }

#pragma unroll
    for (int ks = 0; ks < 2; ++ks) {
      const int ch = ks * 4 + fko;                    // logical 16B chunk
      const int aoff = arow * BK + ((ch ^ l7) << 3);  // same swizzle as write
      const int boff = brow * BK + ((ch ^ l7) << 3);
      i32x4 fah = *(const i32x4*)&AhS[aoff];
      i32x4 fal = *(const i32x4*)&AlS[aoff];
      i32x4 fbh0 = *(const i32x4*)&WhS[boff];
      i32x4 fbl0 = *(const i32x4*)&WlS[boff];
      i32x4 fbh1 = *(const i32x4*)&WhS[boff + 16 * BK];
      i32x4 fbl1 = *(const i32x4*)&WlS[boff + 16 * BK];
      // (Ah+Al)*(Wh+Wl): 4 terms per tile, all into the same accumulator
      acc0 = mfma_bf16(fah, fbh0, acc0);
      acc1 = mfma_bf16(fah, fbh1, acc1);
      acc0 = mfma_bf16(fal, fbh0, acc0);
      acc1 = mfma_bf16(fal, fbh1, acc1);
      acc0 = mfma_bf16(fah, fbl0, acc0);
      acc1 = mfma_bf16(fah, fbl1, acc1);
      acc0 = mfma_bf16(fal, fbl0, acc0);
      acc1 = mfma_bf16(fal, fbl1, acc1);
    }
    if (kc >= HDIM) break;
    __syncthreads();
  }

  // logits -> LDS (reuse staging memory; all waves past final compute barrier)
  __syncthreads();
  float* L = (float*)smem;  // [64][LP]
#pragma unroll
  for (int r = 0; r < 4; ++r) {
    const int row = tg * 16 + fko * 4 + r;  // C/D row mapping
    L[row * LP + eg * 32 + l15] = acc0[r];
    L[row * LP + eg * 32 + 16 + l15] = acc1[r];
  }
  __syncthreads();

  // softmax + top-2: 8 waves x 8 tokens, lane = expert (proven epilogue)
  const int wv8 = tid >> 6;
#pragma unroll
  for (int r = 0; r < 8; ++r) {
    const int lt = wv8 * 8 + r;
    const int tok = bt * BM + lt;
    const float l = L[lt * LP + lane];

    float m = l;
#pragma unroll
    for (int off = 32; off >= 1; off >>= 1) m = fmaxf(m, __shfl_xor(m, off, 64));

    const float e = expf(l - m);
    float sum = e;
#pragma unroll
    for (int off = 32; off >= 1; off >>= 1) sum += __shfl_xor(sum, off, 64);

    const float p = e / sum;
    out[(size_t)tok * NE + lane] = p;

    float m0 = p;
#pragma unroll
    for (int off = 32; off >= 1; off >>= 1) m0 = fmaxf(m0, __shfl_xor(m0, off, 64));
    const unsigned long long b0 = __ballot(p == m0);
    const int i0 = __ffsll(b0) - 1;

    const float pm = (lane == i0) ? -1.f : p;
    float m1 = pm;
#pragma unroll
    for (int off = 32; off >= 1; off >>= 1) m1 = fmaxf(m1, __shfl_xor(m1, off, 64));
    const unsigned long long b1 = __ballot(pm == m1);
    const int i1 = __ffsll(b1) - 1;

    if (lane == 0) {
      float* idxo = out + (size_t)TOKENS * NE + (size_t)tok * 2;
      idxo[0] = (float)i0;
      idxo[1] = (float)i1;
      float* wo = out + (size_t)TOKENS * NE + (size_t)TOKENS * 2 + (size_t)tok * 2;
      const float d = m0 + m1;
      wo[0] = m0 / d;
      wo[1] = m1 / d;
    }
  }
}

extern "C" void kernel_launch(void* const* d_in, const int* in_sizes, int n_in,
                              void* d_out, int out_size, void* d_ws, size_t ws_size,
                              hipStream_t stream) {
  const float* A = (const float*)d_in[0];  // hidden_states [16384, 4096] f32
  const float* W = (const float*)d_in[1];  // gate_weight   [64, 4096] f32
  float* out = (float*)d_out;
  unsigned short* Whi = (unsigned short*)d_ws;          // 512 KiB
  unsigned short* Wlo = Whi + (size_t)NE * HDIM;        // 512 KiB

  convert_w<<<dim3(NE * HDIM / (256 * 8)), 256, 0, stream>>>(W, Whi, Wlo);
  router_mfma<<<dim3(TOKENS / BM), 512, 0, stream>>>(A, Whi, Wlo, out);
}

// Round 3
// 394.155 us; speedup vs baseline: 1.0038x; 1.0038x over previous
//
#include <hip/hip_runtime.h>
#include <math.h>

// B=4, S=4096 -> 16384 tokens; H=4096; E=64; TOP_K=2
#define TOKENS 16384
#define HDIM 4096
#define NE 64

#define BM 64   // tokens per block
#define BK 64   // k per LDS stage (2 mfma k-steps)
#define NT (HDIM / BK)  // 64 K-tiles
#define LP 68   // logits LDS row stride (floats)
#define TSZ (BM * BK)   // one sub-tile in bf16 elems (4096)

typedef float f32x4 __attribute__((ext_vector_type(4)));
typedef int i32x4 __attribute__((ext_vector_type(4)));
typedef __bf16 bf16x8 __attribute__((ext_vector_type(8)));

// f32 -> (hi, lo) bf16 split of 8 elements; each packed as 4xint = 8 bf16.
// a ~= hi + lo with residual ~2^-18|a| -> 3-term MFMA reproduces ~f32 accuracy.
__device__ __forceinline__ void split8(f32x4 v0, f32x4 v1, i32x4& h, i32x4& l) {
  float x[8];
#pragma unroll
  for (int j = 0; j < 4; ++j) { x[j] = v0[j]; x[4 + j] = v1[j]; }
  union { unsigned short u[8]; i32x4 v; } H, L;
#pragma unroll
  for (int j = 0; j < 8; ++j) {
    __bf16 hb = (__bf16)x[j];
    H.u[j] = __builtin_bit_cast(unsigned short, hb);
    L.u[j] = __builtin_bit_cast(unsigned short, (__bf16)(x[j] - (float)hb));
  }
  h = H.v; l = L.v;
}

__device__ __forceinline__ f32x4 mfma_bf16(i32x4 a, i32x4 b, f32x4 c) {
  return __builtin_amdgcn_mfma_f32_16x16x32_bf16(
      __builtin_bit_cast(bf16x8, a), __builtin_bit_cast(bf16x8, b), c, 0, 0, 0);
}

// Pre-split W (64x4096 f32 -> bf16 hi/lo in workspace). ~2 us once.
__global__ __launch_bounds__(256) void convert_w(const float* __restrict__ W,
                                                 unsigned short* __restrict__ Wh,
                                                 unsigned short* __restrict__ Wl) {
  const int i = (blockIdx.x * 256 + threadIdx.x) * 8;
  f32x4 v0 = *(const f32x4*)(W + i);
  f32x4 v1 = *(const f32x4*)(W + i + 4);
  i32x4 h, l;
  split8(v0, v1, h, l);
  *(i32x4*)(Wh + i) = h;
  *(i32x4*)(Wl + i) = l;
}

// Fused router, latency-hidden pipeline:
//   double-buffered LDS + 2-tile-deep register prefetch + ONE barrier/tile
//   (stage(t+1) targets buf^1, disjoint from compute(t)'s buf -> no second
//   barrier; loads for t+2 issue before stage(t+1) so the stage waits on a
//   counted vmcnt, giving every load a full ~1600-cycle tile period).
// Maps (staging XOR swizzle, fragments, epilogue) identical to the
// harness-verified round-2 kernel. 3 MFMA terms (AhWh + AlWh + AhWl).
__global__ __launch_bounds__(512, 2) void router_mfma(const float* __restrict__ A,
                                                      const unsigned short* __restrict__ Wh,
                                                      const unsigned short* __restrict__ Wl,
                                                      float* __restrict__ out) {
  __shared__ __align__(16) unsigned short smem[2 * 4 * TSZ];  // 64 KiB (2 bufs)
  unsigned short* buf0 = smem;            // [Ah|Al|Wh|Wl] sub-tiles, 8 KiB each
  unsigned short* buf1 = smem + 4 * TSZ;

  const int tid = threadIdx.x;
  const int bt = blockIdx.x;

  // staging map: row = tid>>3 (0..63), chunk = tid&7 (8 elems = 16 B each)
  const int srow = tid >> 3;
  const int sc = tid & 7;
  const int soff = srow * BK + ((sc ^ (srow & 7)) << 3);

  const float* Ab = A + (size_t)(bt * BM + srow) * HDIM + sc * 8;
  const unsigned short* Whb = Wh + srow * HDIM + sc * 8;  // srow<64 == E
  const unsigned short* Wlb = Wl + srow * HDIM + sc * 8;

  // fragment map: wave -> 16-token group x 32-expert half (2 16x16 tiles)
  const int lane = tid & 63;
  const int wv = tid >> 6;
  const int tg = wv & 3;
  const int eg = wv >> 2;
  const int l15 = lane & 15;
  const int l7 = lane & 7;
  const int fko = lane >> 4;            // k-subgroup 0..3
  const int arow = tg * 16 + l15;       // token row this lane reads
  const int brow = eg * 32 + l15;       // expert row (tile 0); tile 1 = +16

  f32x4 acc0 = {0.f, 0.f, 0.f, 0.f};
  f32x4 acc1 = {0.f, 0.f, 0.f, 0.f};

  // two prefetch register sets (2-tile-deep pipeline)
  f32x4 a0_0, a1_0, a0_1, a1_1;
  i32x4 wh_0, wl_0, wh_1, wl_1;

  auto loadS = [&](int t, f32x4& a0, f32x4& a1, i32x4& wh, i32x4& wl) {
    const int kc = t * BK;
    a0 = *(const f32x4*)(Ab + kc);
    a1 = *(const f32x4*)(Ab + kc + 4);
    wh = *(const i32x4*)(Whb + kc);
    wl = *(const i32x4*)(Wlb + kc);
  };

  auto stage = [&](unsigned short* B, f32x4 a0, f32x4 a1, i32x4 wh, i32x4 wl) {
    i32x4 h, l;
    split8(a0, a1, h, l);
    *(i32x4*)&B[soff] = h;              // Ah
    *(i32x4*)&B[TSZ + soff] = l;        // Al
    *(i32x4*)&B[2 * TSZ + soff] = wh;   // Wh
    *(i32x4*)&B[3 * TSZ + soff] = wl;   // Wl
  };

  auto compute = [&](const unsigned short* B) {
    const unsigned short* AhS = B;
    const unsigned short* AlS = B + TSZ;
    const unsigned short* WhS = B + 2 * TSZ;
    const unsigned short* WlS = B + 3 * TSZ;
#pragma unroll
    for (int ks = 0; ks < 2; ++ks) {
      const int ch = ks * 4 + fko;                    // logical 16B chunk
      const int aoff = arow * BK + ((ch ^ l7) << 3);  // un-swizzle on read
      const int boff = brow * BK + ((ch ^ l7) << 3);
      i32x4 fah = *(const i32x4*)&AhS[aoff];
      i32x4 fal = *(const i32x4*)&AlS[aoff];
      i32x4 fbh0 = *(const i32x4*)&WhS[boff];
      i32x4 fbh1 = *(const i32x4*)&WhS[boff + 16 * BK];
      i32x4 fbl0 = *(const i32x4*)&WlS[boff];
      i32x4 fbl1 = *(const i32x4*)&WlS[boff + 16 * BK];
      acc0 = mfma_bf16(fah, fbh0, acc0);
      acc1 = mfma_bf16(fah, fbh1, acc1);
      acc0 = mfma_bf16(fal, fbh0, acc0);
      acc1 = mfma_bf16(fal, fbh1, acc1);
      acc0 = mfma_bf16(fah, fbl0, acc0);
      acc1 = mfma_bf16(fah, fbl1, acc1);
    }
  };

  // prologue: tile0 -> S0 -> buf0; issue tile1 -> S1
  loadS(0, a0_0, a1_0, wh_0, wl_0);
  stage(buf0, a0_0, a1_0, wh_0, wl_0);
  loadS(1, a0_1, a1_1, wh_1, wl_1);
  __syncthreads();

  for (int t = 0; t < NT; t += 2) {
    compute(buf0);                                     // tile t
    if (t + 2 < NT) loadS(t + 2, a0_0, a1_0, wh_0, wl_0);
    stage(buf1, a0_1, a1_1, wh_1, wl_1);               // tile t+1
    __syncthreads();

    compute(buf1);                                     // tile t+1
    if (t + 3 < NT) loadS(t + 3, a0_1, a1_1, wh_1, wl_1);
    if (t + 2 < NT) stage(buf0, a0_0, a1_0, wh_0, wl_0);  // tile t+2
    __syncthreads();
  }

  // logits -> LDS (aliases buf0 region; buf0's last reader was compute(t=62),
  // behind the final barrier). C/D layout: col=lane&15, row=(lane>>4)*4+reg.
  float* L = (float*)smem;  // [64][LP]
#pragma unroll
  for (int r = 0; r < 4; ++r) {
    const int row = tg * 16 + fko * 4 + r;
    L[row * LP + eg * 32 + l15] = acc0[r];
    L[row * LP + eg * 32 + 16 + l15] = acc1[r];
  }
  __syncthreads();

  // softmax + top-2: 8 waves x 8 tokens, lane = expert (proven epilogue)
  const int wv8 = tid >> 6;
#pragma unroll
  for (int r = 0; r < 8; ++r) {
    const int lt = wv8 * 8 + r;
    const int tok = bt * BM + lt;
    const float l = L[lt * LP + lane];

    float m = l;
#pragma unroll
    for (int off = 32; off >= 1; off >>= 1) m = fmaxf(m, __shfl_xor(m, off, 64));

    const float e = expf(l - m);
    float sum = e;
#pragma unroll
    for (int off = 32; off >= 1; off >>= 1) sum += __shfl_xor(sum, off, 64);

    const float p = e / sum;
    out[(size_t)tok * NE + lane] = p;

    float m0 = p;
#pragma unroll
    for (int off = 32; off >= 1; off >>= 1) m0 = fmaxf(m0, __shfl_xor(m0, off, 64));
    const unsigned long long b0 = __ballot(p == m0);
    const int i0 = __ffsll(b0) - 1;

    const float pm = (lane == i0) ? -1.f : p;
    float m1 = pm;
#pragma unroll
    for (int off = 32; off >= 1; off >>= 1) m1 = fmaxf(m1, __shfl_xor(m1, off, 64));
    const unsigned long long b1 = __ballot(pm == m1);
    const int i1 = __ffsll(b1) - 1;

    if (lane == 0) {
      float* idxo = out + (size_t)TOKENS * NE + (size_t)tok * 2;
      idxo[0] = (float)i0;
      idxo[1] = (float)i1;
      float* wo = out + (size_t)TOKENS * NE + (size_t)TOKENS * 2 + (size_t)tok * 2;
      const float d = m0 + m1;
      wo[0] = m0 / d;
      wo[1] = m1 / d;
    }
  }
}

extern "C" void kernel_launch(void* const* d_in, const int* in_sizes, int n_in,
                              void* d_out, int out_size, void* d_ws, size_t ws_size,
                              hipStream_t stream) {
  const float* A = (const float*)d_in[0];  // hidden_states [16384, 4096] f32
  const float* W = (const float*)d_in[1];  // gate_weight   [64, 4096] f32
  float* out = (float*)d_out;
  unsigned short* Whi = (unsigned short*)d_ws;          // 512 KiB
  unsigned short* Wlo = Whi + (size_t)NE * HDIM;        // 512 KiB

  convert_w<<<dim3(NE * HDIM / (256 * 8)), 256, 0, stream>>>(W, Whi, Wlo);
  router_mfma<<<dim3(TOKENS / BM), 512, 0, stream>>>(A, Whi, Wlo, out);
}